// Round 1
// baseline (45811.581 us; speedup 1.0000x reference)
//
#include <hip/hip_runtime.h>
#include <hip/hip_bf16.h>

// RateRNN: B=128,T=4096,I=128,H=512; h'=0.8h+0.2relu(Wi x + Wr h + br); y=wo.h+bo
#define B_ 128
#define T_ 4096
#define I_ 128
#define H_ 512

typedef __attribute__((ext_vector_type(8))) short short8;
typedef __attribute__((ext_vector_type(4))) float f32x4;

__device__ __forceinline__ unsigned short f2bf(float f) {
  union { float f; unsigned int u; } v; v.f = f;
  unsigned int r = v.u + 0x7FFFu + ((v.u >> 16) & 1u);  // RNE
  return (unsigned short)(r >> 16);
}

__device__ __forceinline__ short8 cvt8(f32x4 a, f32x4 b) {
  union { short8 s; unsigned short u[8]; } r;
#pragma unroll
  for (int j = 0; j < 4; ++j) { r.u[j] = f2bf(a[j]); r.u[4 + j] = f2bf(b[j]); }
  return r.s;
}

// One-time fp32 -> bf16 conversion of w_rec (H*H) and w_in (H*I) into workspace.
__global__ void cvt_w_kernel(const float* __restrict__ w_rec,
                             const float* __restrict__ w_in,
                             unsigned short* __restrict__ wbf) {
  int i = blockIdx.x * blockDim.x + threadIdx.x;
  if (i < H_ * H_) wbf[i] = f2bf(w_rec[i]);
  if (i < H_ * I_) wbf[H_ * H_ + i] = f2bf(w_in[i]);
}

// 8 blocks x 512 threads. Block owns 16 batch rows, all 512 cols.
// Wave w owns cols n0=64w..64w+63 (4 n-tiles of 16). No inter-WG comms.
// MFMA 16x16x32 bf16; layouts (m89/m91-verified):
//   A[m=lane&15][k=(lane>>4)*8+j],  B[k=(lane>>4)*8+j][n=lane&15],
//   C row=(lane>>4)*4+reg, col=lane&15.
template <bool WBF16>
__global__ __launch_bounds__(512, 2)
void rnn_kernel(const float* __restrict__ inputs,
                const float* __restrict__ hidden,
                const float* __restrict__ w_in_f,
                const float* __restrict__ w_rec_f,
                const float* __restrict__ b_rec,
                const float* __restrict__ w_out,
                const float* __restrict__ b_out,
                const unsigned short* __restrict__ wbf,
                float* __restrict__ out) {
  // +8 bf16 row pad -> 16B/row phase shift, even 8-pass ds_read_b128
  __shared__ alignas(16) unsigned short hs[2][16][520];
  __shared__ alignas(16) float ypart[2][8][16];

  const int tid  = threadIdx.x;
  const int wave = tid >> 6;
  const int lane = tid & 63;
  const int q    = lane >> 4;   // quad
  const int c    = lane & 15;   // col-in-tile (C) / batch-row (A)
  const int r0   = blockIdx.x * 16;
  const int n0   = wave * 64;

  // Stage initial h (bf16) into LDS buffer 0.
  for (int e = tid; e < 16 * H_; e += 512) {
    int rr = e >> 9, cc = e & (H_ - 1);
    hs[0][rr][cc] = f2bf(hidden[(size_t)(r0 + rr) * H_ + cc]);
  }

  // Persistent fp32 h in C-fragment layout: hreg[nt][r] = h[r0+q*4+r][n0+nt*16+c]
  f32x4 hreg[4];
  float brec[4], wout[4];
#pragma unroll
  for (int nt = 0; nt < 4; ++nt) {
    const int col = n0 + nt * 16 + c;
    brec[nt] = b_rec[col];
    wout[nt] = w_out[col];
#pragma unroll
    for (int r = 0; r < 4; ++r)
      hreg[nt][r] = hidden[(size_t)(r0 + q * 4 + r) * H_ + col];
  }
  const float bout = b_out[0];

  __syncthreads();

  const unsigned short* wrecb = wbf;            // [H][H] bf16
  const unsigned short* winb  = wbf + H_ * H_;  // [H][I] bf16
  const size_t wr_off = (size_t)(n0 + c) * H_ + q * 8;
  const size_t wi_off = (size_t)(n0 + c) * I_ + q * 8;
  const float* xbase = inputs + (size_t)(r0 + c) * T_ * I_ + q * 8;

#pragma unroll 2
  for (int t = 0; t < T_; ++t) {
    const int rb = t & 1, wb = rb ^ 1;

    // x_t A-fragment loads issued early (latency hidden under rec MFMAs).
    f32x4 xf[4][2];
    const float* xp = xbase + (size_t)t * I_;
#pragma unroll
    for (int kk = 0; kk < 4; ++kk) {
      xf[kk][0] = *(const f32x4*)(xp + kk * 32);
      xf[kk][1] = *(const f32x4*)(xp + kk * 32 + 4);
    }

    f32x4 acc[4];
#pragma unroll
    for (int nt = 0; nt < 4; ++nt) acc[nt] = (f32x4){0.f, 0.f, 0.f, 0.f};

    // rec = h @ w_rec^T : K=512 (16 k-steps), N=64 per wave (4 n-tiles)
    const unsigned short* hrow = &hs[rb][c][q * 8];
#pragma unroll
    for (int kk = 0; kk < 16; ++kk) {
      short8 a = *(const short8*)(hrow + kk * 32);
#pragma unroll
      for (int nt = 0; nt < 4; ++nt) {
        short8 b;
        if constexpr (WBF16) {
          b = *(const short8*)(wrecb + wr_off + (size_t)nt * 16 * H_ + kk * 32);
        } else {
          const float* p = w_rec_f + wr_off + (size_t)nt * 16 * H_ + kk * 32;
          b = cvt8(*(const f32x4*)p, *(const f32x4*)(p + 4));
        }
        acc[nt] = __builtin_amdgcn_mfma_f32_16x16x32_bf16(a, b, acc[nt], 0, 0, 0);
      }
    }

    // + x_t @ w_in^T : K=128 (4 k-steps)
#pragma unroll
    for (int kk = 0; kk < 4; ++kk) {
      short8 ax = cvt8(xf[kk][0], xf[kk][1]);
#pragma unroll
      for (int nt = 0; nt < 4; ++nt) {
        short8 b;
        if constexpr (WBF16) {
          b = *(const short8*)(winb + wi_off + (size_t)nt * 16 * I_ + kk * 32);
        } else {
          const float* p = w_in_f + wi_off + (size_t)nt * 16 * I_ + kk * 32;
          b = cvt8(*(const f32x4*)p, *(const f32x4*)(p + 4));
        }
        acc[nt] = __builtin_amdgcn_mfma_f32_16x16x32_bf16(ax, b, acc[nt], 0, 0, 0);
      }
    }

    // Epilogue: relu, leaky update (fp32 master state), bf16 h -> LDS, y partials.
    float yp[4] = {0.f, 0.f, 0.f, 0.f};
#pragma unroll
    for (int nt = 0; nt < 4; ++nt) {
#pragma unroll
      for (int r = 0; r < 4; ++r) {
        float act = fmaxf(acc[nt][r] + brec[nt], 0.f);
        float h = hreg[nt][r] * 0.8f + 0.2f * act;
        hreg[nt][r] = h;
        hs[wb][q * 4 + r][n0 + nt * 16 + c] = f2bf(h);
        yp[r] = __builtin_fmaf(wout[nt], h, yp[r]);
      }
    }
    // reduce y over the 16 cols within each quad
#pragma unroll
    for (int off = 8; off >= 1; off >>= 1) {
#pragma unroll
      for (int r = 0; r < 4; ++r) yp[r] += __shfl_xor(yp[r], off, 64);
    }
    if (c == 0)
      *(f32x4*)&ypart[wb][wave][q * 4] = (f32x4){yp[0], yp[1], yp[2], yp[3]};

    __syncthreads();

    if (tid < 16) {
      float s = bout;
#pragma unroll
      for (int w = 0; w < 8; ++w) s += ypart[wb][w][tid];
      out[(size_t)(r0 + tid) * T_ + t] = s;
    }
  }

  // h_final (fp32, full precision from registers)
  float* hfin = out + (size_t)B_ * T_;
#pragma unroll
  for (int nt = 0; nt < 4; ++nt)
#pragma unroll
    for (int r = 0; r < 4; ++r)
      hfin[(size_t)(r0 + q * 4 + r) * H_ + n0 + nt * 16 + c] = hreg[nt][r];
}

extern "C" void kernel_launch(void* const* d_in, const int* in_sizes, int n_in,
                              void* d_out, int out_size, void* d_ws, size_t ws_size,
                              hipStream_t stream) {
  const float* inputs = (const float*)d_in[0];
  const float* hidden = (const float*)d_in[1];
  const float* w_in   = (const float*)d_in[2];
  const float* w_rec  = (const float*)d_in[3];
  const float* b_rec  = (const float*)d_in[4];
  const float* w_out  = (const float*)d_in[5];
  const float* b_out  = (const float*)d_in[6];
  float* out = (float*)d_out;

  const size_t need = (size_t)(H_ * H_ + H_ * I_) * sizeof(unsigned short);
  if (ws_size >= need) {
    unsigned short* wbf = (unsigned short*)d_ws;
    cvt_w_kernel<<<dim3((H_ * H_ + 255) / 256), dim3(256), 0, stream>>>(w_rec, w_in, wbf);
    rnn_kernel<true><<<dim3(8), dim3(512), 0, stream>>>(
        inputs, hidden, w_in, w_rec, b_rec, w_out, b_out, wbf, out);
  } else {
    rnn_kernel<false><<<dim3(8), dim3(512), 0, stream>>>(
        inputs, hidden, w_in, w_rec, b_rec, w_out, b_out, (const unsigned short*)nullptr, out);
  }
}

// Round 2
// 32610.016 us; speedup vs baseline: 1.4048x; 1.4048x over previous
//
#include <hip/hip_runtime.h>
#include <hip/hip_bf16.h>

// RateRNN: B=128,T=4096,I=128,H=512; h'=0.8h+0.2relu(Wi x + Wr h + br); y=wo.h+bo
#define B_ 128
#define T_ 4096
#define I_ 128
#define H_ 512

typedef __attribute__((ext_vector_type(8))) short short8;
typedef __attribute__((ext_vector_type(4))) float f32x4;
typedef __attribute__((ext_vector_type(4))) unsigned short us4;

__device__ __forceinline__ unsigned short f2bf(float f) {
  union { float f; unsigned int u; } v; v.f = f;
  unsigned int r = v.u + 0x7FFFu + ((v.u >> 16) & 1u);  // RNE
  return (unsigned short)(r >> 16);
}

__device__ __forceinline__ short8 cvt8(f32x4 a, f32x4 b) {
  union { short8 s; unsigned short u[8]; } r;
#pragma unroll
  for (int j = 0; j < 4; ++j) { r.u[j] = f2bf(a[j]); r.u[4 + j] = f2bf(b[j]); }
  return r.s;
}

// ---- workspace layout (bytes) ----
#define WBF_BYTES ((size_t)(H_ * H_ + H_ * I_) * 2)            // 655360
#define CNT_OFF   WBF_BYTES                                    // 8 x u32
#define HX_OFF    (CNT_OFF + 32)                               // 655392 (16B aligned)
#define HX_BYTES  ((size_t)8 * 2 * 16 * H_ * 2)                // 262144
#define YP_OFF    (((HX_OFF + HX_BYTES) + 63) & ~(size_t)63)   // 917568
#define YP_BYTES  ((size_t)8 * T_ * 8 * 16 * 4)                // 16777216
#define WS_NEED   (YP_OFF + YP_BYTES)

// One-time fp32 -> bf16 conversion of w_rec, w_in; also zeroes pair counters.
__global__ void cvt_w_kernel(const float* __restrict__ w_rec,
                             const float* __restrict__ w_in,
                             unsigned short* __restrict__ wbf,
                             unsigned int* __restrict__ cnt) {
  int i = blockIdx.x * blockDim.x + threadIdx.x;
  if (i < H_ * H_) wbf[i] = f2bf(w_rec[i]);
  if (i < H_ * I_) wbf[H_ * H_ + i] = f2bf(w_in[i]);
  if (cnt != nullptr && i < 8) cnt[i] = 0;
}

// ---------------------------------------------------------------------------
// Pair kernel: 16 blocks x 256 threads (4 waves, 1 wave/SIMD so ~470 VGPRs ok).
// pair = blockIdx%8 owns batch rows pair*16..+15; half = blockIdx/8 owns cols
// half*256..+255; wave owns 64 cols (n0). Weights register-resident (320 VGPR).
// Operand-swapped MFMA: A = weight tile (m=g), B = h^T (n=batch).
//   A[m=lane&15][k=q*8+j], B[k=q*8+j][n=lane&15], C row=q*4+r (g), col=c (batch).
// Cross-block h exchange via L2 (hx double-buffered by step parity); sync via
// monotone per-pair wave counter (8 waves/pair), acquire/release agent scope.
// ---------------------------------------------------------------------------
__global__ __launch_bounds__(256, 1)
void rnn_pair_kernel(const float* __restrict__ inputs,
                     const float* __restrict__ hidden,
                     const float* __restrict__ b_rec,
                     const float* __restrict__ w_out,
                     const unsigned short* __restrict__ wbf,
                     unsigned short* __restrict__ hx,
                     unsigned int* __restrict__ cnt,
                     float* __restrict__ ypartial,
                     float* __restrict__ hfin) {
  const int tid  = threadIdx.x;
  const int wave = tid >> 6;
  const int lane = tid & 63;
  const int q    = lane >> 4;
  const int c    = lane & 15;
  const int pair = blockIdx.x & 7;
  const int half = blockIdx.x >> 3;
  const int wip  = half * 4 + wave;      // wave id within pair (0..7)
  const int r0   = pair * 16;
  const int n0   = half * 256 + wave * 64;

  // ---- weights -> registers (persistent for all 4096 steps) ----
  short8 wr[16][4], wi[4][4];
  {
    const unsigned short* wrp = wbf + (size_t)(n0 + c) * H_ + q * 8;
    const unsigned short* wip_ = wbf + (size_t)H_ * H_ + (size_t)(n0 + c) * I_ + q * 8;
#pragma unroll
    for (int kk = 0; kk < 16; ++kk)
#pragma unroll
      for (int nt = 0; nt < 4; ++nt)
        wr[kk][nt] = *(const short8*)(wrp + (size_t)nt * 16 * H_ + kk * 32);
#pragma unroll
    for (int kk = 0; kk < 4; ++kk)
#pragma unroll
      for (int nt = 0; nt < 4; ++nt)
        wi[kk][nt] = *(const short8*)(wip_ + (size_t)nt * 16 * I_ + kk * 32);
  }

  // Persistent fp32 state in C-layout: hreg[nt][r] = h[b=r0+c][g=n0+nt*16+q*4+r]
  f32x4 hreg[4], brec[4], wout[4];
#pragma unroll
  for (int nt = 0; nt < 4; ++nt)
#pragma unroll
    for (int r = 0; r < 4; ++r) {
      const int g = n0 + nt * 16 + q * 4 + r;
      hreg[nt][r] = hidden[(size_t)(r0 + c) * H_ + g];
      brec[nt][r] = b_rec[g];
      wout[nt][r] = w_out[g];
    }

  unsigned int* mycnt = cnt + pair;
  unsigned short* hx0 = hx + (size_t)(pair * 2) * 16 * H_;  // slot 0
  unsigned short* hx1 = hx0 + 16 * H_;                      // slot 1

  const float* xbase = inputs + (size_t)(r0 + c) * T_ * I_ + q * 8;

  // prefetch x(0)
  f32x4 xn[4][2];
#pragma unroll
  for (int kk = 0; kk < 4; ++kk) {
    xn[kk][0] = *(const f32x4*)(xbase + kk * 32);
    xn[kk][1] = *(const f32x4*)(xbase + kk * 32 + 4);
  }

  // publish phase 0: h(0) -> slot 0
#pragma unroll
  for (int nt = 0; nt < 4; ++nt) {
    us4 hb;
#pragma unroll
    for (int r = 0; r < 4; ++r) hb[r] = f2bf(hreg[nt][r]);
    *(us4*)(hx0 + (size_t)c * H_ + n0 + nt * 16 + q * 4) = hb;
  }
  if (lane == 0)
    __hip_atomic_fetch_add(mycnt, 1u, __ATOMIC_RELEASE, __HIP_MEMORY_SCOPE_AGENT);

  for (int t = 0; t < T_; ++t) {
    // wait for all 8 waves of the pair to have published phase t
    const unsigned target = 8u * (unsigned)(t + 1);
    while (__hip_atomic_load(mycnt, __ATOMIC_ACQUIRE, __HIP_MEMORY_SCOPE_AGENT) < target) {}

    // convert this step's x (prefetched last iter), then issue next prefetch
    short8 xc[4];
#pragma unroll
    for (int kk = 0; kk < 4; ++kk) xc[kk] = cvt8(xn[kk][0], xn[kk][1]);
    {
      const float* xp = xbase + (size_t)((t + 1 < T_) ? (t + 1) : t) * I_;
#pragma unroll
      for (int kk = 0; kk < 4; ++kk) {
        xn[kk][0] = *(const f32x4*)(xp + kk * 32);
        xn[kk][1] = *(const f32x4*)(xp + kk * 32 + 4);
      }
    }

    const unsigned short* hr = ((t & 1) ? hx1 : hx0) + (size_t)c * H_ + q * 8;

    f32x4 acc[4];
#pragma unroll
    for (int nt = 0; nt < 4; ++nt) acc[nt] = (f32x4){0.f, 0.f, 0.f, 0.f};

    // rec = W_rec(regs) x h^T(L2), 4-deep load pipeline on the B fragments
    short8 hb4[4];
#pragma unroll
    for (int kk = 0; kk < 4; ++kk) hb4[kk] = *(const short8*)(hr + kk * 32);
#pragma unroll
    for (int kk = 0; kk < 16; ++kk) {
      short8 b = hb4[kk & 3];
      if (kk < 12) hb4[kk & 3] = *(const short8*)(hr + (kk + 4) * 32);
#pragma unroll
      for (int nt = 0; nt < 4; ++nt)
        acc[nt] = __builtin_amdgcn_mfma_f32_16x16x32_bf16(wr[kk][nt], b, acc[nt], 0, 0, 0);
    }
    // + W_in(regs) x x^T
#pragma unroll
    for (int kk = 0; kk < 4; ++kk)
#pragma unroll
      for (int nt = 0; nt < 4; ++nt)
        acc[nt] = __builtin_amdgcn_mfma_f32_16x16x32_bf16(wi[kk][nt], xc[kk], acc[nt], 0, 0, 0);

    // epilogue: relu + leaky update (fp32 master), publish bf16 h, y partial
    float yl = 0.f;
    unsigned short* hw = (t & 1) ? hx0 : hx1;  // slot (t+1)&1
#pragma unroll
    for (int nt = 0; nt < 4; ++nt) {
      us4 hb;
#pragma unroll
      for (int r = 0; r < 4; ++r) {
        float act = fmaxf(acc[nt][r] + brec[nt][r], 0.f);
        float h = hreg[nt][r] * 0.8f + 0.2f * act;
        hreg[nt][r] = h;
        hb[r] = f2bf(h);
        yl = __builtin_fmaf(wout[nt][r], h, yl);
      }
      if (t + 1 < T_)
        *(us4*)(hw + (size_t)c * H_ + n0 + nt * 16 + q * 4) = hb;
    }
    // reduce y over g within this wave: lanes {l, l^16, l^32, l^48} share batch c
    yl += __shfl_xor(yl, 16, 64);
    yl += __shfl_xor(yl, 32, 64);
    if (q == 0)
      ypartial[(((size_t)pair * T_ + t) * 8 + wip) * 16 + c] = yl;

    if (t + 1 < T_ && lane == 0)
      __hip_atomic_fetch_add(mycnt, 1u, __ATOMIC_RELEASE, __HIP_MEMORY_SCOPE_AGENT);
  }

  // h_final (fp32, coalesced dwordx4)
#pragma unroll
  for (int nt = 0; nt < 4; ++nt)
    *(f32x4*)(hfin + (size_t)(r0 + c) * H_ + n0 + nt * 16 + q * 4) = hreg[nt];
}

// Sum the 8 per-wave partials into out[b][t] (+ b_out).
__global__ void reduce_y_kernel(const float* __restrict__ ypartial,
                                const float* __restrict__ b_out,
                                float* __restrict__ out) {
  const int idx = blockIdx.x * 256 + threadIdx.x;  // 524288 = B*T
  const int t = idx & (T_ - 1);
  const int r = idx >> 12;        // batch row 0..127
  const int p = r >> 4, b = r & 15;
  const float* yp = ypartial + (((size_t)p * T_ + t) * 8) * 16 + b;
  float s = b_out[0];
#pragma unroll
  for (int w = 0; w < 8; ++w) s += yp[w * 16];
  out[(size_t)r * T_ + t] = s;
}

// ---------------------------------------------------------------------------
// Fallback (round-1 kernel) for small workspace.
// ---------------------------------------------------------------------------
template <bool WBF16>
__global__ __launch_bounds__(512, 2)
void rnn_kernel_fb(const float* __restrict__ inputs,
                   const float* __restrict__ hidden,
                   const float* __restrict__ w_in_f,
                   const float* __restrict__ w_rec_f,
                   const float* __restrict__ b_rec,
                   const float* __restrict__ w_out,
                   const float* __restrict__ b_out,
                   const unsigned short* __restrict__ wbf,
                   float* __restrict__ out) {
  __shared__ alignas(16) unsigned short hs[2][16][520];
  __shared__ alignas(16) float ypart[2][8][16];

  const int tid  = threadIdx.x;
  const int wave = tid >> 6;
  const int lane = tid & 63;
  const int q    = lane >> 4;
  const int c    = lane & 15;
  const int r0   = blockIdx.x * 16;
  const int n0   = wave * 64;

  for (int e = tid; e < 16 * H_; e += 512) {
    int rr = e >> 9, cc = e & (H_ - 1);
    hs[0][rr][cc] = f2bf(hidden[(size_t)(r0 + rr) * H_ + cc]);
  }

  f32x4 hreg[4];
  float brec[4], wout[4];
#pragma unroll
  for (int nt = 0; nt < 4; ++nt) {
    const int col = n0 + nt * 16 + c;
    brec[nt] = b_rec[col];
    wout[nt] = w_out[col];
#pragma unroll
    for (int r = 0; r < 4; ++r)
      hreg[nt][r] = hidden[(size_t)(r0 + q * 4 + r) * H_ + col];
  }
  const float bout = b_out[0];
  __syncthreads();

  const unsigned short* wrecb = wbf;
  const unsigned short* winb  = wbf + H_ * H_;
  const size_t wr_off = (size_t)(n0 + c) * H_ + q * 8;
  const size_t wi_off = (size_t)(n0 + c) * I_ + q * 8;
  const float* xbase = inputs + (size_t)(r0 + c) * T_ * I_ + q * 8;

#pragma unroll 2
  for (int t = 0; t < T_; ++t) {
    const int rb = t & 1, wb = rb ^ 1;
    f32x4 xf[4][2];
    const float* xp = xbase + (size_t)t * I_;
#pragma unroll
    for (int kk = 0; kk < 4; ++kk) {
      xf[kk][0] = *(const f32x4*)(xp + kk * 32);
      xf[kk][1] = *(const f32x4*)(xp + kk * 32 + 4);
    }
    f32x4 acc[4];
#pragma unroll
    for (int nt = 0; nt < 4; ++nt) acc[nt] = (f32x4){0.f, 0.f, 0.f, 0.f};
    const unsigned short* hrow = &hs[rb][c][q * 8];
#pragma unroll
    for (int kk = 0; kk < 16; ++kk) {
      short8 a = *(const short8*)(hrow + kk * 32);
#pragma unroll
      for (int nt = 0; nt < 4; ++nt) {
        short8 b;
        if constexpr (WBF16) {
          b = *(const short8*)(wrecb + wr_off + (size_t)nt * 16 * H_ + kk * 32);
        } else {
          const float* p = w_rec_f + wr_off + (size_t)nt * 16 * H_ + kk * 32;
          b = cvt8(*(const f32x4*)p, *(const f32x4*)(p + 4));
        }
        acc[nt] = __builtin_amdgcn_mfma_f32_16x16x32_bf16(a, b, acc[nt], 0, 0, 0);
      }
    }
#pragma unroll
    for (int kk = 0; kk < 4; ++kk) {
      short8 ax = cvt8(xf[kk][0], xf[kk][1]);
#pragma unroll
      for (int nt = 0; nt < 4; ++nt) {
        short8 b;
        if constexpr (WBF16) {
          b = *(const short8*)(winb + wi_off + (size_t)nt * 16 * I_ + kk * 32);
        } else {
          const float* p = w_in_f + wi_off + (size_t)nt * 16 * I_ + kk * 32;
          b = cvt8(*(const f32x4*)p, *(const f32x4*)(p + 4));
        }
        acc[nt] = __builtin_amdgcn_mfma_f32_16x16x32_bf16(ax, b, acc[nt], 0, 0, 0);
      }
    }
    float yp2[4] = {0.f, 0.f, 0.f, 0.f};
#pragma unroll
    for (int nt = 0; nt < 4; ++nt) {
#pragma unroll
      for (int r = 0; r < 4; ++r) {
        float act = fmaxf(acc[nt][r] + brec[nt], 0.f);
        float h = hreg[nt][r] * 0.8f + 0.2f * act;
        hreg[nt][r] = h;
        hs[wb][q * 4 + r][n0 + nt * 16 + c] = f2bf(h);
        yp2[r] = __builtin_fmaf(wout[nt], h, yp2[r]);
      }
    }
#pragma unroll
    for (int off = 8; off >= 1; off >>= 1) {
#pragma unroll
      for (int r = 0; r < 4; ++r) yp2[r] += __shfl_xor(yp2[r], off, 64);
    }
    if (c == 0)
      *(f32x4*)&ypart[wb][wave][q * 4] = (f32x4){yp2[0], yp2[1], yp2[2], yp2[3]};
    __syncthreads();
    if (tid < 16) {
      float s = bout;
#pragma unroll
      for (int w = 0; w < 8; ++w) s += ypart[wb][w][tid];
      out[(size_t)(r0 + tid) * T_ + t] = s;
    }
  }
  float* hfin = out + (size_t)B_ * T_;
#pragma unroll
  for (int nt = 0; nt < 4; ++nt)
#pragma unroll
    for (int r = 0; r < 4; ++r)
      hfin[(size_t)(r0 + q * 4 + r) * H_ + n0 + nt * 16 + c] = hreg[nt][r];
}

extern "C" void kernel_launch(void* const* d_in, const int* in_sizes, int n_in,
                              void* d_out, int out_size, void* d_ws, size_t ws_size,
                              hipStream_t stream) {
  const float* inputs = (const float*)d_in[0];
  const float* hidden = (const float*)d_in[1];
  const float* w_in   = (const float*)d_in[2];
  const float* w_rec  = (const float*)d_in[3];
  const float* b_rec  = (const float*)d_in[4];
  const float* w_out  = (const float*)d_in[5];
  const float* b_out  = (const float*)d_in[6];
  float* out = (float*)d_out;

  if (ws_size >= WS_NEED) {
    unsigned short* wbf = (unsigned short*)d_ws;
    unsigned int*   cnt = (unsigned int*)((char*)d_ws + CNT_OFF);
    unsigned short* hx  = (unsigned short*)((char*)d_ws + HX_OFF);
    float*          yp  = (float*)((char*)d_ws + YP_OFF);
    float*          hfin = out + (size_t)B_ * T_;
    cvt_w_kernel<<<dim3((H_ * H_ + 255) / 256), dim3(256), 0, stream>>>(w_rec, w_in, wbf, cnt);
    rnn_pair_kernel<<<dim3(16), dim3(256), 0, stream>>>(
        inputs, hidden, b_rec, w_out, wbf, hx, cnt, yp, hfin);
    reduce_y_kernel<<<dim3((B_ * T_) / 256), dim3(256), 0, stream>>>(yp, b_out, out);
  } else if (ws_size >= WBF_BYTES) {
    unsigned short* wbf = (unsigned short*)d_ws;
    cvt_w_kernel<<<dim3((H_ * H_ + 255) / 256), dim3(256), 0, stream>>>(w_rec, w_in, wbf, nullptr);
    rnn_kernel_fb<true><<<dim3(8), dim3(512), 0, stream>>>(
        inputs, hidden, w_in, w_rec, b_rec, w_out, b_out, wbf, out);
  } else {
    rnn_kernel_fb<false><<<dim3(8), dim3(512), 0, stream>>>(
        inputs, hidden, w_in, w_rec, b_rec, w_out, b_out, (const unsigned short*)nullptr, out);
  }
}